// Round 1
// baseline (981.252 us; speedup 1.0000x reference)
//
#include <hip/hip_runtime.h>
#include <hip/hip_bf16.h>

#define BB 1024
#define NSLOT 32
#define DD 1024
#define HH 4096

typedef __bf16 bfx8 __attribute__((ext_vector_type(8)));
typedef float f32x4 __attribute__((ext_vector_type(4)));

__device__ __forceinline__ unsigned short f2bfu(float f) {
  union { float f; unsigned u; } v; v.f = f;
  unsigned r = v.u + 0x7fffu + ((v.u >> 16) & 1u);
  return (unsigned short)(r >> 16);
}
__device__ __forceinline__ float bfu2f(unsigned short u) {
  union { unsigned u; float f; } v; v.u = ((unsigned)u) << 16; return v.f;
}
__device__ __forceinline__ float gelu_f(float x) {
  return 0.5f * x * (1.0f + erff(x * 0.70710678118654752f));
}
__device__ __forceinline__ float sigm(float x) { return 1.0f / (1.0f + expf(-x)); }

// ---------------- conversion / transpose kernels ----------------

// x [B,D] f32 -> ctx[:, 0:D] bf16 (ctx row stride 2*D)
__global__ __launch_bounds__(256) void cvt_x_ctx(const float* __restrict__ x,
                                                 unsigned short* __restrict__ ctx) {
  int i = blockIdx.x * 256 + threadIdx.x;      // over B*D/4
  int b = i >> 8;                               // D/4 = 256 vec4 per row
  int c4 = (i & 255) * 4;
  float4 v = ((const float4*)(x + (size_t)b * DD))[i & 255];
  ushort4 o; o.x = f2bfu(v.x); o.y = f2bfu(v.y); o.z = f2bfu(v.z); o.w = f2bfu(v.w);
  *(ushort4*)&ctx[(size_t)b * (2 * DD) + c4] = o;
}

// flat f32 -> bf16, vectorized x4
__global__ __launch_bounds__(256) void cvt4(const float* __restrict__ in,
                                            unsigned short* __restrict__ out, int n4) {
  int i = blockIdx.x * 256 + threadIdx.x;
  if (i >= n4) return;
  float4 v = ((const float4*)in)[i];
  ushort4 o; o.x = f2bfu(v.x); o.y = f2bfu(v.y); o.z = f2bfu(v.z); o.w = f2bfu(v.w);
  ((ushort4*)out)[i] = o;
}

// slot_mean over NS slots (reads bf16 S) -> ctx[:, D:2D]
__global__ __launch_bounds__(256) void slot_mean_k(const unsigned short* __restrict__ Sb,
                                                   unsigned short* __restrict__ ctx) {
  int i = blockIdx.x * 256 + threadIdx.x;      // over B*D
  int b = i >> 10, d = i & 1023;
  const unsigned short* p = Sb + (size_t)b * NSLOT * DD + d;
  float s = 0.f;
  #pragma unroll
  for (int sl = 0; sl < NSLOT; sl++) s += bfu2f(p[sl * DD]);
  ctx[(size_t)b * (2 * DD) + DD + d] = f2bfu(s * (1.0f / NSLOT));
}

// out[c][r] = bf16(in[r][c]) ; grid (C/32, R/32), 256 thr
__global__ __launch_bounds__(256) void transp(const float* __restrict__ in,
                                              unsigned short* __restrict__ out,
                                              int R, int C) {
  __shared__ float t[32][33];
  int tx = threadIdx.x & 31, ty = threadIdx.x >> 5;  // ty 0..7
  int c0 = blockIdx.x * 32, r0 = blockIdx.y * 32;
  #pragma unroll
  for (int i = 0; i < 4; i++) {
    int r = r0 + ty * 4 + i;
    t[ty * 4 + i][tx] = in[(size_t)r * C + c0 + tx];
  }
  __syncthreads();
  #pragma unroll
  for (int i = 0; i < 4; i++) {
    int c = c0 + ty * 4 + i;
    out[(size_t)c * R + r0 + tx] = f2bfu(t[tx][ty * 4 + i]);
  }
}

// ---------------- generic NT bf16 MFMA GEMM ----------------
// C[M,N] = A[M,K] @ Bt[N,K]^T ; tile 128x64, 256 thr = 4 waves, wave = 32 rows
// EPI 0: outF = acc            (fp32, no bias)
// EPI 1: outB = bf16(gelu(acc + bias[col]))
// EPI 2: outF = acc + bias[col] + add[row*ldadd+col]
template <int EPI>
__global__ __launch_bounds__(256) void gemm_nt(
    const unsigned short* __restrict__ A, int lda,
    const unsigned short* __restrict__ Bt, int ldb, int K,
    const float* __restrict__ bias,
    const float* __restrict__ add, int ldadd,
    float* __restrict__ outF, unsigned short* __restrict__ outB, int ldout) {
  __shared__ __align__(16) unsigned short lA[128 * 40];
  __shared__ __align__(16) unsigned short lB[64 * 40];
  const int tid = threadIdx.x;
  const int wave = tid >> 6, lane = tid & 63;
  const int q = lane >> 4, l15 = lane & 15;
  const int row0 = blockIdx.y * 128;
  const int col0 = blockIdx.x * 64;
  const int ar = tid >> 2;          // 0..63
  const int ac = (tid & 3) * 8;     // 0,8,16,24

  f32x4 acc[2][4];
  #pragma unroll
  for (int m = 0; m < 2; m++)
    #pragma unroll
    for (int n = 0; n < 4; n++) acc[m][n] = (f32x4){0.f, 0.f, 0.f, 0.f};

  for (int k0 = 0; k0 < K; k0 += 32) {
    *(uint4*)&lA[ar * 40 + ac] = *(const uint4*)&A[(size_t)(row0 + ar) * lda + k0 + ac];
    *(uint4*)&lA[(ar + 64) * 40 + ac] = *(const uint4*)&A[(size_t)(row0 + ar + 64) * lda + k0 + ac];
    *(uint4*)&lB[ar * 40 + ac] = *(const uint4*)&Bt[(size_t)(col0 + ar) * ldb + k0 + ac];
    __syncthreads();
    bfx8 af[2], bf[4];
    #pragma unroll
    for (int m = 0; m < 2; m++)
      af[m] = *(const bfx8*)&lA[(wave * 32 + m * 16 + l15) * 40 + q * 8];
    #pragma unroll
    for (int n = 0; n < 4; n++)
      bf[n] = *(const bfx8*)&lB[(n * 16 + l15) * 40 + q * 8];
    #pragma unroll
    for (int m = 0; m < 2; m++)
      #pragma unroll
      for (int n = 0; n < 4; n++)
        acc[m][n] = __builtin_amdgcn_mfma_f32_16x16x32_bf16(af[m], bf[n], acc[m][n], 0, 0, 0);
    __syncthreads();
  }

  #pragma unroll
  for (int m = 0; m < 2; m++) {
    #pragma unroll
    for (int n = 0; n < 4; n++) {
      int gr0 = row0 + wave * 32 + m * 16 + q * 4;
      int gc = col0 + n * 16 + l15;
      #pragma unroll
      for (int i = 0; i < 4; i++) {
        int gr = gr0 + i;
        float v = acc[m][n][i];
        if (EPI == 0) {
          outF[(size_t)gr * ldout + gc] = v;
        } else if (EPI == 1) {
          float t = gelu_f(v + bias[gc]);
          outB[(size_t)gr * ldout + gc] = f2bfu(t);
        } else {
          outF[(size_t)gr * ldout + gc] = v + bias[gc] + add[(size_t)gr * ldadd + gc];
        }
      }
    }
  }
}

// ---------------- fused GRU GEMM: gh = S @ w_hh (3 gates) + gate math ----------------
// A = Sb [B*NS, D] bf16 ; Whht [3D, D] bf16 (transposed) ; grid (D/64, B*NS/128)
__global__ __launch_bounds__(256) void gru_gemm(
    const unsigned short* __restrict__ Sb, const unsigned short* __restrict__ Whht,
    const float* __restrict__ alpha, const float* __restrict__ xw,
    const float* __restrict__ b_ih, const float* __restrict__ b_hh,
    const float* __restrict__ Sf, float* __restrict__ Snew) {
  __shared__ __align__(16) unsigned short lA[128 * 40];
  __shared__ __align__(16) unsigned short lB[3][64 * 40];
  const int tid = threadIdx.x;
  const int wave = tid >> 6, lane = tid & 63;
  const int q = lane >> 4, l15 = lane & 15;
  const int row0 = blockIdx.y * 128;
  const int col0 = blockIdx.x * 64;
  const int ar = tid >> 2;
  const int ac = (tid & 3) * 8;

  f32x4 acc[3][2][4];
  #pragma unroll
  for (int g = 0; g < 3; g++)
    #pragma unroll
    for (int m = 0; m < 2; m++)
      #pragma unroll
      for (int n = 0; n < 4; n++) acc[g][m][n] = (f32x4){0.f, 0.f, 0.f, 0.f};

  for (int k0 = 0; k0 < DD; k0 += 32) {
    *(uint4*)&lA[ar * 40 + ac] = *(const uint4*)&Sb[(size_t)(row0 + ar) * DD + k0 + ac];
    *(uint4*)&lA[(ar + 64) * 40 + ac] = *(const uint4*)&Sb[(size_t)(row0 + ar + 64) * DD + k0 + ac];
    #pragma unroll
    for (int g = 0; g < 3; g++)
      *(uint4*)&lB[g][ar * 40 + ac] =
          *(const uint4*)&Whht[((size_t)g * DD + col0 + ar) * DD + k0 + ac];
    __syncthreads();
    bfx8 af[2];
    #pragma unroll
    for (int m = 0; m < 2; m++)
      af[m] = *(const bfx8*)&lA[(wave * 32 + m * 16 + l15) * 40 + q * 8];
    #pragma unroll
    for (int g = 0; g < 3; g++) {
      bfx8 bf[4];
      #pragma unroll
      for (int n = 0; n < 4; n++)
        bf[n] = *(const bfx8*)&lB[g][(n * 16 + l15) * 40 + q * 8];
      #pragma unroll
      for (int m = 0; m < 2; m++)
        #pragma unroll
        for (int n = 0; n < 4; n++)
          acc[g][m][n] = __builtin_amdgcn_mfma_f32_16x16x32_bf16(af[m], bf[n], acc[g][m][n], 0, 0, 0);
    }
    __syncthreads();
  }

  #pragma unroll
  for (int m = 0; m < 2; m++) {
    #pragma unroll
    for (int i = 0; i < 4; i++) {
      int gr = row0 + wave * 32 + m * 16 + q * 4 + i;
      float a = alpha[gr];
      const float* xwr = xw + (size_t)(gr >> 5) * (3 * DD);
      const float* sor = Sf + (size_t)gr * DD;
      float* orow = Snew + (size_t)gr * DD;
      #pragma unroll
      for (int n = 0; n < 4; n++) {
        int gc = col0 + n * 16 + l15;
        float ghr = acc[0][m][n][i] + b_hh[gc];
        float ghz = acc[1][m][n][i] + b_hh[gc + DD];
        float ghn = acc[2][m][n][i] + b_hh[gc + 2 * DD];
        float gir = a * xwr[gc] + b_ih[gc];
        float giz = a * xwr[gc + DD] + b_ih[gc + DD];
        float gin = a * xwr[gc + 2 * DD] + b_ih[gc + 2 * DD];
        float r = sigm(gir + ghr);
        float z = sigm(giz + ghz);
        float nn = tanhf(gin + r * ghn);
        orow[gc] = (1.0f - z) * nn + z * sor[gc];
      }
    }
  }
}

// ---------------- routing logits + softmax ----------------
__global__ __launch_bounds__(256) void route_softmax(
    const unsigned short* __restrict__ h_r, const float* __restrict__ w_r2,
    const float* __restrict__ b_r2, float* __restrict__ alpha_out) {
  int b = blockIdx.x;
  int n = threadIdx.x & 31, c = threadIdx.x >> 5;  // 8 chunks of 128
  __shared__ float part[8][32];
  __shared__ float logits[32];
  const unsigned short* hr = h_r + (size_t)b * DD;
  float s = 0.f;
  for (int i = 0; i < 128; i++) {
    int k = c * 128 + i;
    s += bfu2f(hr[k]) * w_r2[k * NSLOT + n];
  }
  part[c][n] = s;
  __syncthreads();
  if (threadIdx.x < 32) {
    float t = b_r2[n];
    #pragma unroll
    for (int cc = 0; cc < 8; cc++) t += part[cc][n];
    logits[n] = t;
  }
  __syncthreads();
  if (threadIdx.x < 32) {
    float mx = -1e30f;
    #pragma unroll
    for (int j = 0; j < 32; j++) mx = fmaxf(mx, logits[j]);
    float den = 0.f;
    #pragma unroll
    for (int j = 0; j < 32; j++) den += expf(logits[j] - mx);
    alpha_out[(size_t)b * NSLOT + n] = expf(logits[n] - mx) / den;
  }
}

// ---------------- slot context reduction ----------------
__global__ __launch_bounds__(256) void slot_ctx_k(const float* __restrict__ Snew,
                                                  const float* __restrict__ alpha,
                                                  unsigned short* __restrict__ sc_b) {
  int i = blockIdx.x * 256 + threadIdx.x;   // over B*D
  int b = i >> 10, d = i & 1023;
  __shared__ float al[NSLOT];
  if (threadIdx.x < NSLOT) al[threadIdx.x] = alpha[(size_t)(blockIdx.x >> 2) * NSLOT + threadIdx.x];
  __syncthreads();
  const float* p = Snew + (size_t)b * NSLOT * DD + d;
  float s = 0.f;
  #pragma unroll
  for (int sl = 0; sl < NSLOT; sl++) s += al[sl] * p[sl * DD];
  sc_b[i] = f2bfu(s);
}

// ---------------- layernorm ----------------
template <int OUT_BF>
__global__ __launch_bounds__(256) void ln_k(const float* __restrict__ in,
                                            const float* __restrict__ gw,
                                            const float* __restrict__ bw,
                                            float* __restrict__ outF,
                                            unsigned short* __restrict__ outB) {
  int b = blockIdx.x;
  int tid = threadIdx.x;
  float4 v = ((const float4*)(in + (size_t)b * DD))[tid];
  float s = v.x + v.y + v.z + v.w;
  float s2 = v.x * v.x + v.y * v.y + v.z * v.z + v.w * v.w;
  #pragma unroll
  for (int o = 32; o > 0; o >>= 1) { s += __shfl_down(s, o); s2 += __shfl_down(s2, o); }
  __shared__ float as1[4], as2[4];
  int wave = tid >> 6, lane = tid & 63;
  if (lane == 0) { as1[wave] = s; as2[wave] = s2; }
  __syncthreads();
  float t1 = as1[0] + as1[1] + as1[2] + as1[3];
  float t2 = as2[0] + as2[1] + as2[2] + as2[3];
  float mu = t1 * (1.0f / DD);
  float var = t2 * (1.0f / DD) - mu * mu;
  float rstd = rsqrtf(var + 1e-5f);
  int d = tid * 4;
  float o0 = (v.x - mu) * rstd * gw[d] + bw[d];
  float o1 = (v.y - mu) * rstd * gw[d + 1] + bw[d + 1];
  float o2 = (v.z - mu) * rstd * gw[d + 2] + bw[d + 2];
  float o3 = (v.w - mu) * rstd * gw[d + 3] + bw[d + 3];
  if (OUT_BF) {
    ushort4 o; o.x = f2bfu(o0); o.y = f2bfu(o1); o.z = f2bfu(o2); o.w = f2bfu(o3);
    *(ushort4*)&outB[(size_t)b * DD + d] = o;
  } else {
    float4 o; o.x = o0; o.y = o1; o.z = o2; o.w = o3;
    *(float4*)&outF[(size_t)b * DD + d] = o;
  }
}

// ---------------- launch ----------------
extern "C" void kernel_launch(void* const* d_in, const int* in_sizes, int n_in,
                              void* d_out, int out_size, void* d_ws, size_t ws_size,
                              hipStream_t stream) {
  const float* x      = (const float*)d_in[0];
  const float* S      = (const float*)d_in[1];
  const float* w_r1   = (const float*)d_in[2];
  const float* b_r1   = (const float*)d_in[3];
  const float* w_r2   = (const float*)d_in[4];
  const float* b_r2   = (const float*)d_in[5];
  const float* b_ih   = (const float*)d_in[8];
  const float* b_hh   = (const float*)d_in[9];
  const float* w_ih   = (const float*)d_in[6];
  const float* w_hh   = (const float*)d_in[7];
  const float* w_proj = (const float*)d_in[10];
  const float* b_proj = (const float*)d_in[11];
  const float* ln1_g  = (const float*)d_in[12];
  const float* ln1_b  = (const float*)d_in[13];
  const float* w_f1   = (const float*)d_in[14];
  const float* b_f1   = (const float*)d_in[15];
  const float* w_f2   = (const float*)d_in[16];
  const float* b_f2   = (const float*)d_in[17];
  const float* ln2_g  = (const float*)d_in[18];
  const float* ln2_b  = (const float*)d_in[19];

  float* out_x = (float*)d_out;
  float* out_S = out_x + (size_t)BB * DD;
  float* out_a = out_S + (size_t)BB * NSLOT * DD;

  char* ws = (char*)d_ws;
  unsigned short* ctx    = (unsigned short*)(ws + 0);             // 4 MB [B][2D]
  unsigned short* w_r1t  = (unsigned short*)(ws + 4194304);       // 4 MB [D][2D]
  unsigned short* w_iht  = (unsigned short*)(ws + 8388608);       // 6 MB [3D][D]
  unsigned short* w_hht  = (unsigned short*)(ws + 14680064);      // 6 MB [3D][D]
  unsigned short* w_projt= (unsigned short*)(ws + 20971520);      // 2 MB [D][D]
  unsigned short* w_f1t  = (unsigned short*)(ws + 23068672);      // 8 MB [H][D]
  unsigned short* w_f2t  = (unsigned short*)(ws + 31457280);      // 8 MB [D][H]
  unsigned short* h_r    = (unsigned short*)(ws + 39845888);      // 2 MB [B][D]
  float*          xw     = (float*)(ws + 41943040);               // 12 MB [B][3D]
  unsigned short* Sb     = (unsigned short*)(ws + 54525952);      // 64 MB [B*NS][D]
  // aliases (lifetimes don't overlap originals):
  unsigned short* sc_b   = (unsigned short*)(ws + 0);             // reuse ctx (dead after xw GEMM)
  float*          x_mid  = (float*)(ws + 41943040);               // reuse xw (dead after gru)
  unsigned short* h_ln   = (unsigned short*)(ws + 46137344);      // xw + 4MB
  float*          pre2   = (float*)(ws + 48234496);               // xw + 6MB
  unsigned short* ff1    = (unsigned short*)(ws + 54525952);      // reuse Sb (dead after gru)

  dim3 blk(256);
  // --- prep: conversions + weight transposes ---
  cvt_x_ctx<<<1024, blk, 0, stream>>>(x, ctx);
  cvt4<<<32768, blk, 0, stream>>>(S, Sb, (BB * NSLOT * DD) / 4);
  slot_mean_k<<<4096, blk, 0, stream>>>(Sb, ctx);
  transp<<<dim3(32, 64), blk, 0, stream>>>(w_r1, w_r1t, 2 * DD, DD);
  transp<<<dim3(96, 32), blk, 0, stream>>>(w_ih, w_iht, DD, 3 * DD);
  transp<<<dim3(96, 32), blk, 0, stream>>>(w_hh, w_hht, DD, 3 * DD);
  transp<<<dim3(32, 32), blk, 0, stream>>>(w_proj, w_projt, DD, DD);
  transp<<<dim3(128, 32), blk, 0, stream>>>(w_f1, w_f1t, DD, HH);
  transp<<<dim3(32, 128), blk, 0, stream>>>(w_f2, w_f2t, HH, DD);

  // --- routing ---
  gemm_nt<1><<<dim3(16, 8), blk, 0, stream>>>(ctx, 2 * DD, w_r1t, 2 * DD, 2 * DD,
                                              b_r1, nullptr, 0, nullptr, h_r, DD);
  route_softmax<<<1024, blk, 0, stream>>>(h_r, w_r2, b_r2, out_a);

  // --- xw = x @ w_ih (rank-1 trick: gi = alpha * xw) ---
  gemm_nt<0><<<dim3(48, 8), blk, 0, stream>>>(ctx, 2 * DD, w_iht, DD, DD,
                                              nullptr, nullptr, 0, xw, nullptr, 3 * DD);

  // --- fused GRU: gh GEMM + gates + S_new ---
  gru_gemm<<<dim3(16, 256), blk, 0, stream>>>(Sb, w_hht, out_a, xw, b_ih, b_hh, S, out_S);

  // --- readout + proj + residual ---
  slot_ctx_k<<<4096, blk, 0, stream>>>(out_S, out_a, sc_b);
  gemm_nt<2><<<dim3(16, 8), blk, 0, stream>>>(sc_b, DD, w_projt, DD, DD,
                                              b_proj, x, DD, x_mid, nullptr, DD);

  // --- LN1 -> FFN -> LN2 ---
  ln_k<1><<<1024, blk, 0, stream>>>(x_mid, ln1_g, ln1_b, nullptr, h_ln);
  gemm_nt<1><<<dim3(64, 8), blk, 0, stream>>>(h_ln, DD, w_f1t, DD, DD,
                                              b_f1, nullptr, 0, nullptr, ff1, HH);
  gemm_nt<2><<<dim3(16, 8), blk, 0, stream>>>(ff1, HH, w_f2t, HH, HH,
                                              b_f2, x_mid, DD, pre2, nullptr, DD);
  ln_k<0><<<1024, blk, 0, stream>>>(pre2, ln2_g, ln2_b, out_x, nullptr);
}

// Round 2
// 906.565 us; speedup vs baseline: 1.0824x; 1.0824x over previous
//
#include <hip/hip_runtime.h>
#include <hip/hip_bf16.h>

#define BB 1024
#define NSLOT 32
#define DD 1024
#define HH 4096

typedef __bf16 bfx8 __attribute__((ext_vector_type(8)));
typedef float f32x4 __attribute__((ext_vector_type(4)));

__device__ __forceinline__ unsigned short f2bfu(float f) {
  union { float f; unsigned u; } v; v.f = f;
  unsigned r = v.u + 0x7fffu + ((v.u >> 16) & 1u);
  return (unsigned short)(r >> 16);
}
__device__ __forceinline__ float bfu2f(unsigned short u) {
  union { unsigned u; float f; } v; v.u = ((unsigned)u) << 16; return v.f;
}
__device__ __forceinline__ float gelu_f(float x) {
  return 0.5f * x * (1.0f + erff(x * 0.70710678118654752f));
}
__device__ __forceinline__ float sigm(float x) { return 1.0f / (1.0f + expf(-x)); }

// async global->LDS, 16B per lane; LDS dest = wave-uniform base + lane*16
__device__ __forceinline__ void async16(const unsigned short* g, unsigned short* l) {
  __builtin_amdgcn_global_load_lds(
      (const __attribute__((address_space(1))) unsigned int*)g,
      (__attribute__((address_space(3))) unsigned int*)l, 16, 0, 0);
}

// ---------------- conversion / transpose kernels ----------------

__global__ __launch_bounds__(256) void cvt_x_ctx(const float* __restrict__ x,
                                                 unsigned short* __restrict__ ctx) {
  int i = blockIdx.x * 256 + threadIdx.x;
  int b = i >> 8;
  int c4 = (i & 255) * 4;
  float4 v = ((const float4*)(x + (size_t)b * DD))[i & 255];
  ushort4 o; o.x = f2bfu(v.x); o.y = f2bfu(v.y); o.z = f2bfu(v.z); o.w = f2bfu(v.w);
  *(ushort4*)&ctx[(size_t)b * (2 * DD) + c4] = o;
}

__global__ __launch_bounds__(256) void cvt4(const float* __restrict__ in,
                                            unsigned short* __restrict__ out, int n4) {
  int i = blockIdx.x * 256 + threadIdx.x;
  if (i >= n4) return;
  float4 v = ((const float4*)in)[i];
  ushort4 o; o.x = f2bfu(v.x); o.y = f2bfu(v.y); o.z = f2bfu(v.z); o.w = f2bfu(v.w);
  ((ushort4*)out)[i] = o;
}

__global__ __launch_bounds__(256) void slot_mean_k(const unsigned short* __restrict__ Sb,
                                                   unsigned short* __restrict__ ctx) {
  int i = blockIdx.x * 256 + threadIdx.x;
  int b = i >> 10, d = i & 1023;
  const unsigned short* p = Sb + (size_t)b * NSLOT * DD + d;
  float s = 0.f;
  #pragma unroll
  for (int sl = 0; sl < NSLOT; sl++) s += bfu2f(p[sl * DD]);
  ctx[(size_t)b * (2 * DD) + DD + d] = f2bfu(s * (1.0f / NSLOT));
}

__global__ __launch_bounds__(256) void transp(const float* __restrict__ in,
                                              unsigned short* __restrict__ out,
                                              int R, int C) {
  __shared__ float t[32][33];
  int tx = threadIdx.x & 31, ty = threadIdx.x >> 5;
  int c0 = blockIdx.x * 32, r0 = blockIdx.y * 32;
  #pragma unroll
  for (int i = 0; i < 4; i++) {
    int r = r0 + ty * 4 + i;
    t[ty * 4 + i][tx] = in[(size_t)r * C + c0 + tx];
  }
  __syncthreads();
  #pragma unroll
  for (int i = 0; i < 4; i++) {
    int c = c0 + ty * 4 + i;
    out[(size_t)c * R + r0 + tx] = f2bfu(t[tx][ty * 4 + i]);
  }
}

// ---------------- generic NT bf16 MFMA GEMM (unchanged this round) ----------------
template <int EPI>
__global__ __launch_bounds__(256) void gemm_nt(
    const unsigned short* __restrict__ A, int lda,
    const unsigned short* __restrict__ Bt, int ldb, int K,
    const float* __restrict__ bias,
    const float* __restrict__ add, int ldadd,
    float* __restrict__ outF, unsigned short* __restrict__ outB, int ldout) {
  __shared__ __align__(16) unsigned short lA[128 * 40];
  __shared__ __align__(16) unsigned short lB[64 * 40];
  const int tid = threadIdx.x;
  const int wave = tid >> 6, lane = tid & 63;
  const int q = lane >> 4, l15 = lane & 15;
  const int row0 = blockIdx.y * 128;
  const int col0 = blockIdx.x * 64;
  const int ar = tid >> 2;
  const int ac = (tid & 3) * 8;

  f32x4 acc[2][4];
  #pragma unroll
  for (int m = 0; m < 2; m++)
    #pragma unroll
    for (int n = 0; n < 4; n++) acc[m][n] = (f32x4){0.f, 0.f, 0.f, 0.f};

  for (int k0 = 0; k0 < K; k0 += 32) {
    *(uint4*)&lA[ar * 40 + ac] = *(const uint4*)&A[(size_t)(row0 + ar) * lda + k0 + ac];
    *(uint4*)&lA[(ar + 64) * 40 + ac] = *(const uint4*)&A[(size_t)(row0 + ar + 64) * lda + k0 + ac];
    *(uint4*)&lB[ar * 40 + ac] = *(const uint4*)&Bt[(size_t)(col0 + ar) * ldb + k0 + ac];
    __syncthreads();
    bfx8 af[2], bf[4];
    #pragma unroll
    for (int m = 0; m < 2; m++)
      af[m] = *(const bfx8*)&lA[(wave * 32 + m * 16 + l15) * 40 + q * 8];
    #pragma unroll
    for (int n = 0; n < 4; n++)
      bf[n] = *(const bfx8*)&lB[(n * 16 + l15) * 40 + q * 8];
    #pragma unroll
    for (int m = 0; m < 2; m++)
      #pragma unroll
      for (int n = 0; n < 4; n++)
        acc[m][n] = __builtin_amdgcn_mfma_f32_16x16x32_bf16(af[m], bf[n], acc[m][n], 0, 0, 0);
    __syncthreads();
  }

  #pragma unroll
  for (int m = 0; m < 2; m++) {
    #pragma unroll
    for (int n = 0; n < 4; n++) {
      int gr0 = row0 + wave * 32 + m * 16 + q * 4;
      int gc = col0 + n * 16 + l15;
      #pragma unroll
      for (int i = 0; i < 4; i++) {
        int gr = gr0 + i;
        float v = acc[m][n][i];
        if (EPI == 0) {
          outF[(size_t)gr * ldout + gc] = v;
        } else if (EPI == 1) {
          float t = gelu_f(v + bias[gc]);
          outB[(size_t)gr * ldout + gc] = f2bfu(t);
        } else {
          outF[(size_t)gr * ldout + gc] = v + bias[gc] + add[(size_t)gr * ldadd + gc];
        }
      }
    }
  }
}

// ---------------- fused GRU GEMM (m97-style) + gates + slot-context ----------------
// A = Sb [B*NS, D] bf16 ; Whht [3D, D] bf16 ; grid (D/64, B*NS/128), 256 thr.
// Tile: 128 rows x 64 cols x 3 gates, BK=64 (2 halves of 32).
// Staging via global_load_lds w=16; LDS rows 64B, XOR chunk swizzle c^((r>>1)&3)
// (maps 16 frag rows onto all 8 bank-groups twice -> free 2-way).
// Epilogue: GRU gates + S_new (fp32) + fused alpha-weighted slot-context (bf16).
__global__ __launch_bounds__(256) void gru_gemm(
    const unsigned short* __restrict__ Sb, const unsigned short* __restrict__ Whht,
    const float* __restrict__ alpha, const float* __restrict__ xw,
    const float* __restrict__ b_ih, const float* __restrict__ b_hh,
    const float* __restrict__ Sf, float* __restrict__ Snew,
    unsigned short* __restrict__ sc_b) {
  __shared__ __align__(16) unsigned short lA[2][128 * 32];   // 16 KB
  __shared__ __align__(16) unsigned short lB[2][192 * 32];   // 24 KB
  const int tid = threadIdx.x;
  const int wave = tid >> 6, lane = tid & 63;
  const int wr = wave >> 1, wc = wave & 1;
  const int q = lane >> 4, l15 = lane & 15;
  const int row0 = blockIdx.y * 128;
  const int col0 = blockIdx.x * 64;
  const int halfA = 128 * 32, halfB = 192 * 32;

  // ---- staging descriptors (loop-invariant; advance by 64 elems/iter) ----
  const int lr = lane >> 2, scn = lane & 3;
  const unsigned short* aSrc[2];
  unsigned short* aDst[2];
  #pragma unroll
  for (int j = 0; j < 2; j++) {
    int R0 = (2 * wave + j) * 16;
    int r = R0 + lr;
    int c = scn ^ ((r >> 1) & 3);
    aSrc[j] = Sb + (size_t)(row0 + r) * DD + c * 8;
    aDst[j] = &lA[0][R0 * 32];
  }
  const unsigned short* bSrc[3];
  unsigned short* bDst[3];
  #pragma unroll
  for (int j = 0; j < 3; j++) {
    int R0 = (3 * wave + j) * 16;
    int r = R0 + lr;
    int g = r >> 6, cr = r & 63;
    int c = scn ^ ((r >> 1) & 3);
    bSrc[j] = Whht + ((size_t)g * DD + col0 + cr) * DD + c * 8;
    bDst[j] = &lB[0][R0 * 32];
  }

  // ---- fragment read offsets (loop-invariant, swizzled) ----
  int offA[4];
  #pragma unroll
  for (int m = 0; m < 4; m++) {
    int r = wr * 64 + m * 16 + l15;
    offA[m] = r * 32 + (q ^ ((r >> 1) & 3)) * 8;
  }
  int offB[3][2];
  #pragma unroll
  for (int g = 0; g < 3; g++)
    #pragma unroll
    for (int n = 0; n < 2; n++) {
      int r = g * 64 + wc * 32 + n * 16 + l15;
      offB[g][n] = r * 32 + (q ^ ((r >> 1) & 3)) * 8;
    }

  f32x4 acc[3][4][2];
  #pragma unroll
  for (int g = 0; g < 3; g++)
    #pragma unroll
    for (int m = 0; m < 4; m++)
      #pragma unroll
      for (int n = 0; n < 2; n++) acc[g][m][n] = (f32x4){0.f, 0.f, 0.f, 0.f};

  // ---- K loop: 16 iters of BK=64 ----
  for (int it = 0; it < 16; it++) {
    #pragma unroll
    for (int j = 0; j < 2; j++) {
      async16(aSrc[j], aDst[j]);
      async16(aSrc[j] + 32, aDst[j] + halfA);
      aSrc[j] += 64;
    }
    #pragma unroll
    for (int j = 0; j < 3; j++) {
      async16(bSrc[j], bDst[j]);
      async16(bSrc[j] + 32, bDst[j] + halfB);
      bSrc[j] += 64;
    }
    __syncthreads();   // drains vmcnt -> staged data visible
    #pragma unroll
    for (int h = 0; h < 2; h++) {
      bfx8 af[4];
      #pragma unroll
      for (int m = 0; m < 4; m++) af[m] = *(const bfx8*)&lA[h][offA[m]];
      #pragma unroll
      for (int g = 0; g < 3; g++) {
        bfx8 bf0 = *(const bfx8*)&lB[h][offB[g][0]];
        bfx8 bf1 = *(const bfx8*)&lB[h][offB[g][1]];
        #pragma unroll
        for (int m = 0; m < 4; m++) {
          acc[g][m][0] = __builtin_amdgcn_mfma_f32_16x16x32_bf16(af[m], bf0, acc[g][m][0], 0, 0, 0);
          acc[g][m][1] = __builtin_amdgcn_mfma_f32_16x16x32_bf16(af[m], bf1, acc[g][m][1], 0, 0, 0);
        }
      }
    }
    __syncthreads();   // protect LDS from next iter's staging
  }

  // ---- epilogue: gates + S_new + fused slot-context ----
  float scp[2][2] = {{0.f, 0.f}, {0.f, 0.f}};
  #pragma unroll
  for (int m = 0; m < 4; m++) {
    #pragma unroll
    for (int i = 0; i < 4; i++) {
      int gr = row0 + wr * 64 + m * 16 + q * 4 + i;
      float a = alpha[gr];
      const float* xwr = xw + (size_t)(gr >> 5) * (3 * DD);
      const float* sfr = Sf + (size_t)gr * DD;
      float* orow = Snew + (size_t)gr * DD;
      #pragma unroll
      for (int n = 0; n < 2; n++) {
        int gc = col0 + wc * 32 + n * 16 + l15;
        float ghr = acc[0][m][n][i] + b_hh[gc];
        float ghz = acc[1][m][n][i] + b_hh[gc + DD];
        float ghn = acc[2][m][n][i] + b_hh[gc + 2 * DD];
        float r = sigm(a * xwr[gc] + b_ih[gc] + ghr);
        float z = sigm(a * xwr[gc + DD] + b_ih[gc + DD] + ghz);
        float nn = tanhf(a * xwr[gc + 2 * DD] + b_ih[gc + 2 * DD] + r * ghn);
        float sv = (1.0f - z) * nn + z * sfr[gc];
        orow[gc] = sv;
        scp[m >> 1][n] += a * sv;
      }
    }
  }
  #pragma unroll
  for (int bh = 0; bh < 2; bh++)
    #pragma unroll
    for (int n = 0; n < 2; n++) {
      float v = scp[bh][n];
      v += __shfl_xor(v, 16);
      v += __shfl_xor(v, 32);
      if (q == 0) {
        int batch = (row0 >> 5) + wr * 2 + bh;
        int gc = col0 + wc * 32 + n * 16 + l15;
        sc_b[(size_t)batch * DD + gc] = f2bfu(v);
      }
    }
}

// ---------------- routing logits + softmax ----------------
__global__ __launch_bounds__(256) void route_softmax(
    const unsigned short* __restrict__ h_r, const float* __restrict__ w_r2,
    const float* __restrict__ b_r2, float* __restrict__ alpha_out) {
  int b = blockIdx.x;
  int n = threadIdx.x & 31, c = threadIdx.x >> 5;
  __shared__ float part[8][32];
  __shared__ float logits[32];
  const unsigned short* hr = h_r + (size_t)b * DD;
  float s = 0.f;
  for (int i = 0; i < 128; i++) {
    int k = c * 128 + i;
    s += bfu2f(hr[k]) * w_r2[k * NSLOT + n];
  }
  part[c][n] = s;
  __syncthreads();
  if (threadIdx.x < 32) {
    float t = b_r2[n];
    #pragma unroll
    for (int cc = 0; cc < 8; cc++) t += part[cc][n];
    logits[n] = t;
  }
  __syncthreads();
  if (threadIdx.x < 32) {
    float mx = -1e30f;
    #pragma unroll
    for (int j = 0; j < 32; j++) mx = fmaxf(mx, logits[j]);
    float den = 0.f;
    #pragma unroll
    for (int j = 0; j < 32; j++) den += expf(logits[j] - mx);
    alpha_out[(size_t)b * NSLOT + n] = expf(logits[n] - mx) / den;
  }
}

// ---------------- layernorm ----------------
template <int OUT_BF>
__global__ __launch_bounds__(256) void ln_k(const float* __restrict__ in,
                                            const float* __restrict__ gw,
                                            const float* __restrict__ bw,
                                            float* __restrict__ outF,
                                            unsigned short* __restrict__ outB) {
  int b = blockIdx.x;
  int tid = threadIdx.x;
  float4 v = ((const float4*)(in + (size_t)b * DD))[tid];
  float s = v.x + v.y + v.z + v.w;
  float s2 = v.x * v.x + v.y * v.y + v.z * v.z + v.w * v.w;
  #pragma unroll
  for (int o = 32; o > 0; o >>= 1) { s += __shfl_down(s, o); s2 += __shfl_down(s2, o); }
  __shared__ float as1[4], as2[4];
  int wave = tid >> 6, lane = tid & 63;
  if (lane == 0) { as1[wave] = s; as2[wave] = s2; }
  __syncthreads();
  float t1 = as1[0] + as1[1] + as1[2] + as1[3];
  float t2 = as2[0] + as2[1] + as2[2] + as2[3];
  float mu = t1 * (1.0f / DD);
  float var = t2 * (1.0f / DD) - mu * mu;
  float rstd = rsqrtf(var + 1e-5f);
  int d = tid * 4;
  float o0 = (v.x - mu) * rstd * gw[d] + bw[d];
  float o1 = (v.y - mu) * rstd * gw[d + 1] + bw[d + 1];
  float o2 = (v.z - mu) * rstd * gw[d + 2] + bw[d + 2];
  float o3 = (v.w - mu) * rstd * gw[d + 3] + bw[d + 3];
  if (OUT_BF) {
    ushort4 o; o.x = f2bfu(o0); o.y = f2bfu(o1); o.z = f2bfu(o2); o.w = f2bfu(o3);
    *(ushort4*)&outB[(size_t)b * DD + d] = o;
  } else {
    float4 o; o.x = o0; o.y = o1; o.z = o2; o.w = o3;
    *(float4*)&outF[(size_t)b * DD + d] = o;
  }
}

// ---------------- launch ----------------
extern "C" void kernel_launch(void* const* d_in, const int* in_sizes, int n_in,
                              void* d_out, int out_size, void* d_ws, size_t ws_size,
                              hipStream_t stream) {
  const float* x      = (const float*)d_in[0];
  const float* S      = (const float*)d_in[1];
  const float* w_r1   = (const float*)d_in[2];
  const float* b_r1   = (const float*)d_in[3];
  const float* w_r2   = (const float*)d_in[4];
  const float* b_r2   = (const float*)d_in[5];
  const float* w_ih   = (const float*)d_in[6];
  const float* w_hh   = (const float*)d_in[7];
  const float* b_ih   = (const float*)d_in[8];
  const float* b_hh   = (const float*)d_in[9];
  const float* w_proj = (const float*)d_in[10];
  const float* b_proj = (const float*)d_in[11];
  const float* ln1_g  = (const float*)d_in[12];
  const float* ln1_b  = (const float*)d_in[13];
  const float* w_f1   = (const float*)d_in[14];
  const float* b_f1   = (const float*)d_in[15];
  const float* w_f2   = (const float*)d_in[16];
  const float* b_f2   = (const float*)d_in[17];
  const float* ln2_g  = (const float*)d_in[18];
  const float* ln2_b  = (const float*)d_in[19];

  float* out_x = (float*)d_out;
  float* out_S = out_x + (size_t)BB * DD;
  float* out_a = out_S + (size_t)BB * NSLOT * DD;

  char* ws = (char*)d_ws;
  unsigned short* ctx    = (unsigned short*)(ws + 0);             // 4 MB [B][2D]
  unsigned short* w_r1t  = (unsigned short*)(ws + 4194304);       // 4 MB [D][2D]
  unsigned short* w_iht  = (unsigned short*)(ws + 8388608);       // 6 MB [3D][D]
  unsigned short* w_hht  = (unsigned short*)(ws + 14680064);      // 6 MB [3D][D]
  unsigned short* w_projt= (unsigned short*)(ws + 20971520);      // 2 MB [D][D]
  unsigned short* w_f1t  = (unsigned short*)(ws + 23068672);      // 8 MB [H][D]
  unsigned short* w_f2t  = (unsigned short*)(ws + 31457280);      // 8 MB [D][H]
  unsigned short* h_r    = (unsigned short*)(ws + 39845888);      // 2 MB [B][D]
  float*          xw     = (float*)(ws + 41943040);               // 12 MB [B][3D]
  unsigned short* Sb     = (unsigned short*)(ws + 54525952);      // 64 MB [B*NS][D]
  // aliases (lifetimes don't overlap originals):
  unsigned short* sc_b   = (unsigned short*)(ws + 0);             // reuse ctx (dead after xw GEMM)
  float*          x_mid  = (float*)(ws + 41943040);               // reuse xw (dead after gru)
  unsigned short* h_ln   = (unsigned short*)(ws + 46137344);      // xw + 4MB
  float*          pre2   = (float*)(ws + 48234496);               // xw + 6MB
  unsigned short* ff1    = (unsigned short*)(ws + 54525952);      // reuse Sb (dead after gru)

  dim3 blk(256);
  // --- prep: conversions + weight transposes ---
  cvt_x_ctx<<<1024, blk, 0, stream>>>(x, ctx);
  cvt4<<<32768, blk, 0, stream>>>(S, Sb, (BB * NSLOT * DD) / 4);
  slot_mean_k<<<4096, blk, 0, stream>>>(Sb, ctx);
  transp<<<dim3(32, 64), blk, 0, stream>>>(w_r1, w_r1t, 2 * DD, DD);
  transp<<<dim3(96, 32), blk, 0, stream>>>(w_ih, w_iht, DD, 3 * DD);
  transp<<<dim3(96, 32), blk, 0, stream>>>(w_hh, w_hht, DD, 3 * DD);
  transp<<<dim3(32, 32), blk, 0, stream>>>(w_proj, w_projt, DD, DD);
  transp<<<dim3(128, 32), blk, 0, stream>>>(w_f1, w_f1t, DD, HH);
  transp<<<dim3(32, 128), blk, 0, stream>>>(w_f2, w_f2t, HH, DD);

  // --- routing ---
  gemm_nt<1><<<dim3(16, 8), blk, 0, stream>>>(ctx, 2 * DD, w_r1t, 2 * DD, 2 * DD,
                                              b_r1, nullptr, 0, nullptr, h_r, DD);
  route_softmax<<<1024, blk, 0, stream>>>(h_r, w_r2, b_r2, out_a);

  // --- xw = x @ w_ih (rank-1 trick: gi = alpha * xw) ---
  gemm_nt<0><<<dim3(48, 8), blk, 0, stream>>>(ctx, 2 * DD, w_iht, DD, DD,
                                              nullptr, nullptr, 0, xw, nullptr, 3 * DD);

  // --- fused GRU: gh GEMM + gates + S_new + slot-context ---
  gru_gemm<<<dim3(16, 256), blk, 0, stream>>>(Sb, w_hht, out_a, xw, b_ih, b_hh, S,
                                              out_S, sc_b);

  // --- proj + residual ---
  gemm_nt<2><<<dim3(16, 8), blk, 0, stream>>>(sc_b, DD, w_projt, DD, DD,
                                              b_proj, x, DD, x_mid, nullptr, DD);

  // --- LN1 -> FFN -> LN2 ---
  ln_k<1><<<1024, blk, 0, stream>>>(x_mid, ln1_g, ln1_b, nullptr, h_ln);
  gemm_nt<1><<<dim3(64, 8), blk, 0, stream>>>(h_ln, DD, w_f1t, DD, DD,
                                              b_f1, nullptr, 0, nullptr, ff1, HH);
  gemm_nt<2><<<dim3(16, 8), blk, 0, stream>>>(ff1, HH, w_f2t, HH, HH,
                                              b_f2, x_mid, DD, pre2, nullptr, DD);
  ln_k<0><<<1024, blk, 0, stream>>>(pre2, ln2_g, ln2_b, out_x, nullptr);
}